// Round 3
// baseline (473.602 us; speedup 1.0000x reference)
//
#include <hip/hip_runtime.h>

#define D 256

typedef __attribute__((ext_vector_type(8))) short bf16x8;
typedef __attribute__((ext_vector_type(4))) float f32x4;

__device__ __forceinline__ unsigned short bfr(float x) {
    unsigned u = __float_as_uint(x);
    unsigned r = (u + 0x7fffu + ((u >> 16) & 1u)) >> 16;
    return (unsigned short)r;
}
__device__ __forceinline__ float bf2f(unsigned short u) {
    return __uint_as_float(((unsigned)u) << 16);
}

// ---------------- fp32 -> bf16 convert ----------------
__global__ void cvt_kernel(const float* __restrict__ in, unsigned short* __restrict__ out, long n4) {
    long stride = (long)gridDim.x * blockDim.x;
    for (long i = (long)blockIdx.x * blockDim.x + threadIdx.x; i < n4; i += stride) {
        float4 v = reinterpret_cast<const float4*>(in)[i];
        ushort4 o;
        o.x = bfr(v.x); o.y = bfr(v.y); o.z = bfr(v.z); o.w = bfr(v.w);
        reinterpret_cast<ushort4*>(out)[i] = o;
    }
}

// ---------------- CSR build ----------------
__global__ void hist_kernel(const int* __restrict__ dst, int* __restrict__ counts, int E) {
    int i = blockIdx.x * blockDim.x + threadIdx.x;
    if (i < E) atomicAdd(&counts[dst[i]], 1);
}

// phase 1: per-block (1024 counts) sums
__global__ void scan1_kernel(const int* __restrict__ counts, int* __restrict__ blocksums, int n) {
    int b = blockIdx.x, t = threadIdx.x;
    int base = b * 1024 + t * 4;
    int s = 0;
    if (base + 3 < n) {
        int4 c = *reinterpret_cast<const int4*>(&counts[base]);
        s = c.x + c.y + c.z + c.w;
    } else {
        for (int i = 0; i < 4; ++i) if (base + i < n) s += counts[base + i];
    }
    int lane = t & 63, w = t >> 6;
    for (int off = 1; off < 64; off <<= 1) s += __shfl_xor(s, off, 64);
    __shared__ int ws_[4];
    if (lane == 0) ws_[w] = s;
    __syncthreads();
    if (t == 0) blocksums[b] = ws_[0] + ws_[1] + ws_[2] + ws_[3];
}

// phase 2: one-wave inclusive scan of block sums (nb <= 64)
__global__ void scan2_kernel(const int* __restrict__ blocksums, int* __restrict__ blockoffs, int nb) {
    int lane = threadIdx.x;
    int v = (lane < nb) ? blocksums[lane] : 0;
    for (int off = 1; off < 64; off <<= 1) {
        int u = __shfl_up(v, off, 64);
        if (lane >= off) v += u;
    }
    if (lane < nb) blockoffs[lane] = v;  // inclusive
}

// phase 3: local scan + block offset -> offsets[1..n]; offsets[0]=0
__global__ void scan3_kernel(const int* __restrict__ counts, const int* __restrict__ blockoffs,
                             int* __restrict__ offsets, int n) {
    int b = blockIdx.x, t = threadIdx.x;
    int base = b * 1024 + t * 4;
    int c0 = 0, c1 = 0, c2 = 0, c3 = 0;
    if (base + 3 < n) {
        int4 c = *reinterpret_cast<const int4*>(&counts[base]);
        c0 = c.x; c1 = c.y; c2 = c.z; c3 = c.w;
    } else {
        if (base + 0 < n) c0 = counts[base + 0];
        if (base + 1 < n) c1 = counts[base + 1];
        if (base + 2 < n) c2 = counts[base + 2];
        if (base + 3 < n) c3 = counts[base + 3];
    }
    int s0 = c0, s1 = s0 + c1, s2 = s1 + c2, s3 = s2 + c3;  // thread-inclusive
    int lane = t & 63, w = t >> 6;
    int v = s3;
    for (int off = 1; off < 64; off <<= 1) {
        int u = __shfl_up(v, off, 64);
        if (lane >= off) v += u;
    }
    __shared__ int wsum[4];
    if (lane == 63) wsum[w] = v;
    __syncthreads();
    int woff = 0;
#pragma unroll
    for (int i = 0; i < 4; ++i) if (i < w) woff += wsum[i];
    int bo = b ? blockoffs[b - 1] : 0;
    int p = bo + woff + (v - s3);  // exclusive prefix for this thread
    if (base + 0 < n) offsets[base + 1] = p + s0;
    if (base + 1 < n) offsets[base + 2] = p + s1;
    if (base + 2 < n) offsets[base + 3] = p + s2;
    if (base + 3 < n) offsets[base + 4] = p + s3;
    if (b == 0 && t == 0) offsets[0] = 0;
}

__global__ void fill_kernel(const int* __restrict__ src, const float* __restrict__ e,
                            const int* __restrict__ dst, const int* __restrict__ offsets,
                            int* __restrict__ cursor, int2* __restrict__ ev, int E) {
    int i = blockIdx.x * blockDim.x + threadIdx.x;
    if (i < E) {
        int d = dst[i];
        int p = offsets[d] + atomicAdd(&cursor[d], 1);
        ev[p] = make_int2(src[i], __float_as_int(e[i]));
    }
}

// ---------------- aggregation: one wave per node, bf16 gather ----------------
__global__ void aggregate_kernel(const unsigned short* __restrict__ hb, const int2* __restrict__ ev,
                                 const int* __restrict__ offsets, unsigned short* __restrict__ hnb,
                                 int n_nodes) {
    int wid = blockIdx.x * 4 + (threadIdx.x >> 6);
    if (wid >= n_nodes) return;
    int lane = threadIdx.x & 63;
    int beg = offsets[wid], end = offsets[wid + 1];
    float ax = 0.f, ay = 0.f, az = 0.f, aw = 0.f;
    int k = beg;
    for (; k + 4 <= end; k += 4) {
        int2 e0 = ev[k], e1 = ev[k + 1], e2 = ev[k + 2], e3 = ev[k + 3];
        ushort4 h0 = *reinterpret_cast<const ushort4*>(&hb[(size_t)e0.x * D + lane * 4]);
        ushort4 h1 = *reinterpret_cast<const ushort4*>(&hb[(size_t)e1.x * D + lane * 4]);
        ushort4 h2 = *reinterpret_cast<const ushort4*>(&hb[(size_t)e2.x * D + lane * 4]);
        ushort4 h3 = *reinterpret_cast<const ushort4*>(&hb[(size_t)e3.x * D + lane * 4]);
        float w0 = __int_as_float(e0.y), w1 = __int_as_float(e1.y);
        float w2 = __int_as_float(e2.y), w3 = __int_as_float(e3.y);
        ax += bf2f(h0.x) * w0 + bf2f(h1.x) * w1 + bf2f(h2.x) * w2 + bf2f(h3.x) * w3;
        ay += bf2f(h0.y) * w0 + bf2f(h1.y) * w1 + bf2f(h2.y) * w2 + bf2f(h3.y) * w3;
        az += bf2f(h0.z) * w0 + bf2f(h1.z) * w1 + bf2f(h2.z) * w2 + bf2f(h3.z) * w3;
        aw += bf2f(h0.w) * w0 + bf2f(h1.w) * w1 + bf2f(h2.w) * w2 + bf2f(h3.w) * w3;
    }
    for (; k < end; ++k) {
        int2 e0 = ev[k];
        ushort4 h0 = *reinterpret_cast<const ushort4*>(&hb[(size_t)e0.x * D + lane * 4]);
        float w0 = __int_as_float(e0.y);
        ax += bf2f(h0.x) * w0; ay += bf2f(h0.y) * w0;
        az += bf2f(h0.z) * w0; aw += bf2f(h0.w) * w0;
    }
    int deg = end - beg;
    float inv = (deg > 0) ? (1.0f / (float)deg) : 0.0f;
    ushort4 o;
    o.x = bfr(ax * inv); o.y = bfr(ay * inv); o.z = bfr(az * inv); o.w = bfr(aw * inv);
    *reinterpret_cast<ushort4*>(&hnb[(size_t)wid * D + lane * 4]) = o;
}

// ---------------- bf16 MFMA GEMM: C[M,256] = relu(A[M,256] @ W[256,256]^T + bias) ----------------
// FUSE_STATS: also emit per-block column sum / sumsq partials (for BatchNorm).
template <int FUSE_STATS>
__global__ __launch_bounds__(256) void gemm_kernel(const unsigned short* __restrict__ A,
                                                   const float* __restrict__ W,
                                                   const float* __restrict__ bias,
                                                   unsigned short* __restrict__ Cout,
                                                   float* __restrict__ partial, int M) {
    __shared__ short As[64 * 256];
    __shared__ short Ws[64 * 256];
    const int t = threadIdx.x;
    const int row0 = blockIdx.x * 64;
    const int col0 = blockIdx.y * 64;

#pragma unroll
    for (int it = 0; it < 8; ++it) {
        int p = it * 4096 + t * 16;
        int r = p >> 9;
        int grow = row0 + r;
        float4 v = make_float4(0.f, 0.f, 0.f, 0.f);
        if (grow < M)
            v = *reinterpret_cast<const float4*>(reinterpret_cast<const char*>(A) +
                                                 (size_t)grow * 512 + (p & 511));
        *reinterpret_cast<float4*>(reinterpret_cast<char*>(As) + (p ^ ((r & 7) << 4))) = v;
    }
#pragma unroll
    for (int it = 0; it < 8; ++it) {
        int p = it * 4096 + t * 16;
        int r = p >> 9;
        const float* wsrc = W + (size_t)(col0 + r) * D + ((p & 511) >> 1);
        float4 w0 = *reinterpret_cast<const float4*>(wsrc);
        float4 w1 = *reinterpret_cast<const float4*>(wsrc + 4);
        bf16x8 pk;
        pk[0] = (short)bfr(w0.x); pk[1] = (short)bfr(w0.y);
        pk[2] = (short)bfr(w0.z); pk[3] = (short)bfr(w0.w);
        pk[4] = (short)bfr(w1.x); pk[5] = (short)bfr(w1.y);
        pk[6] = (short)bfr(w1.z); pk[7] = (short)bfr(w1.w);
        *reinterpret_cast<bf16x8*>(reinterpret_cast<char*>(Ws) + (p ^ ((r & 7) << 4))) = pk;
    }
    __syncthreads();

    const int lane = t & 63;
    const int w = t >> 6;
    const int wr = (w >> 1) * 32;
    const int wc = (w & 1) * 32;
    const int lr = lane & 15;
    const int q = lane >> 4;
    const int swz = (lane & 7) << 4;

    f32x4 zero = {0.f, 0.f, 0.f, 0.f};
    f32x4 acc[2][2] = {{zero, zero}, {zero, zero}};

#pragma unroll
    for (int k0 = 0; k0 < 256; k0 += 32) {
        int kb = k0 * 2 + q * 16;
        bf16x8 a0 = *reinterpret_cast<const bf16x8*>(reinterpret_cast<const char*>(As) +
                                                     (((wr + lr) * 512 + kb) ^ swz));
        bf16x8 a1 = *reinterpret_cast<const bf16x8*>(reinterpret_cast<const char*>(As) +
                                                     (((wr + 16 + lr) * 512 + kb) ^ swz));
        bf16x8 b0 = *reinterpret_cast<const bf16x8*>(reinterpret_cast<const char*>(Ws) +
                                                     (((wc + lr) * 512 + kb) ^ swz));
        bf16x8 b1 = *reinterpret_cast<const bf16x8*>(reinterpret_cast<const char*>(Ws) +
                                                     (((wc + 16 + lr) * 512 + kb) ^ swz));
        acc[0][0] = __builtin_amdgcn_mfma_f32_16x16x32_bf16(a0, b0, acc[0][0], 0, 0, 0);
        acc[0][1] = __builtin_amdgcn_mfma_f32_16x16x32_bf16(a0, b1, acc[0][1], 0, 0, 0);
        acc[1][0] = __builtin_amdgcn_mfma_f32_16x16x32_bf16(a1, b0, acc[1][0], 0, 0, 0);
        acc[1][1] = __builtin_amdgcn_mfma_f32_16x16x32_bf16(a1, b1, acc[1][1], 0, 0, 0);
    }

    float csum[2] = {0.f, 0.f}, csq[2] = {0.f, 0.f};
#pragma unroll
    for (int i = 0; i < 2; ++i) {
#pragma unroll
        for (int j = 0; j < 2; ++j) {
            int col = col0 + wc + j * 16 + lr;
            float bv = bias[col];
#pragma unroll
            for (int r = 0; r < 4; ++r) {
                int row = row0 + wr + i * 16 + q * 4 + r;
                if (row < M) {
                    float v = fmaxf(acc[i][j][r] + bv, 0.f);
                    Cout[(size_t)row * D + col] = bfr(v);
                    if (FUSE_STATS) { csum[j] += v; csq[j] += v * v; }
                }
            }
        }
    }

    if (FUSE_STATS) {
        __shared__ float cs_s[2][2][2][16];
        __shared__ float cq_s[2][2][2][16];
#pragma unroll
        for (int j = 0; j < 2; ++j) {
            float s = csum[j], qq = csq[j];
            s += __shfl_xor(s, 16, 64); s += __shfl_xor(s, 32, 64);
            qq += __shfl_xor(qq, 16, 64); qq += __shfl_xor(qq, 32, 64);
            if (lane < 16) { cs_s[w >> 1][w & 1][j][lane] = s; cq_s[w >> 1][w & 1][j][lane] = qq; }
        }
        __syncthreads();
        if (w < 2 && lane < 16) {
#pragma unroll
            for (int j = 0; j < 2; ++j) {
                int gcol = col0 + (w & 1) * 32 + j * 16 + lane;
                float S = cs_s[0][w & 1][j][lane] + cs_s[1][w & 1][j][lane];
                float Q = cq_s[0][w & 1][j][lane] + cq_s[1][w & 1][j][lane];
                partial[(size_t)blockIdx.x * 512 + gcol] = S;
                partial[(size_t)blockIdx.x * 512 + 256 + gcol] = Q;
            }
        }
    }
}

__global__ void bn_finalize_kernel(const float* __restrict__ partial, const float* __restrict__ gamma,
                                   const float* __restrict__ beta, float* __restrict__ scaleshift,
                                   int nrb, int n) {
    int c = threadIdx.x;
    float s = 0.f, q = 0.f;
    for (int b = 0; b < nrb; ++b) {
        s += partial[(size_t)b * 512 + c];
        q += partial[(size_t)b * 512 + 256 + c];
    }
    float mu = s / (float)n;
    float var = q / (float)n - mu * mu;
    float rs = rsqrtf(var + 1e-5f);
    float sc = gamma[c] * rs;
    scaleshift[c] = sc;
    scaleshift[D + c] = beta[c] - mu * sc;
}

__global__ void bn_apply_kernel(float* __restrict__ out, const unsigned short* __restrict__ x2b,
                                const unsigned short* __restrict__ hnb,
                                const float* __restrict__ scaleshift, long total4) {
    long stride = (long)gridDim.x * blockDim.x;
    for (long i = (long)blockIdx.x * blockDim.x + threadIdx.x; i < total4; i += stride) {
        int c4 = (int)(i & 63);
        ushort4 xu = reinterpret_cast<const ushort4*>(x2b)[i];
        ushort4 hu = reinterpret_cast<const ushort4*>(hnb)[i];
        float4 sc = reinterpret_cast<const float4*>(scaleshift)[c4];
        float4 sh = reinterpret_cast<const float4*>(scaleshift)[64 + c4];
        float4 v;
        v.x = bf2f(xu.x) * sc.x + sh.x + bf2f(hu.x);
        v.y = bf2f(xu.y) * sc.y + sh.y + bf2f(hu.y);
        v.z = bf2f(xu.z) * sc.z + sh.z + bf2f(hu.z);
        v.w = bf2f(xu.w) * sc.w + sh.w + bf2f(hu.w);
        reinterpret_cast<float4*>(out)[i] = v;
    }
}

extern "C" void kernel_launch(void* const* d_in, const int* in_sizes, int n_in,
                              void* d_out, int out_size, void* d_ws, size_t ws_size,
                              hipStream_t stream) {
    const float* h     = (const float*)d_in[0];
    const float* e     = (const float*)d_in[1];
    const int*   src   = (const int*)d_in[2];
    const int*   dst   = (const int*)d_in[3];
    const float* W1    = (const float*)d_in[4];
    const float* b1    = (const float*)d_in[5];
    const float* W2    = (const float*)d_in[6];
    const float* b2    = (const float*)d_in[7];
    const float* gamma = (const float*)d_in[8];
    const float* beta  = (const float*)d_in[9];
    float* out = (float*)d_out;

    const int N = in_sizes[0] / D;
    const int E = in_sizes[2];
    const size_t NB = (size_t)N * D;
    const int nrb = (N + 63) / 64;
    const int nb1 = (N + 1023) / 1024;

    char* ws = (char*)d_ws;
    unsigned short* h_bf = (unsigned short*)ws; ws += NB * 2;   // dead after aggregate
    unsigned short* hnb  = (unsigned short*)ws; ws += NB * 2;
    unsigned short* x1b  = (unsigned short*)ws; ws += NB * 2;
    int2* ev             = (int2*)ws;           ws += (size_t)E * 8;
    float* partial       = (float*)ws;          ws += (size_t)nrb * 512 * 4;
    float* scaleshift    = (float*)ws;          ws += 2 * D * sizeof(float);
    int* offsets         = (int*)ws;            ws += (size_t)(N + 1) * 4;
    int* counts          = (int*)ws;            ws += (size_t)N * 4;
    int* cursor          = (int*)ws;            ws += (size_t)N * 4;
    int* blocksums       = (int*)ws;            ws += 64 * 4;
    int* blockoffs       = (int*)ws;            ws += 64 * 4;
    unsigned short* x2b  = h_bf;                // alias: reuse h_bf region

    hipMemsetAsync(counts, 0, (size_t)2 * N * 4, stream);

    cvt_kernel<<<2048, 256, 0, stream>>>(h, h_bf, (long)(NB / 4));

    int eb = (E + 255) / 256;
    hist_kernel<<<eb, 256, 0, stream>>>(dst, counts, E);
    scan1_kernel<<<nb1, 256, 0, stream>>>(counts, blocksums, N);
    scan2_kernel<<<1, 64, 0, stream>>>(blocksums, blockoffs, nb1);
    scan3_kernel<<<nb1, 256, 0, stream>>>(counts, blockoffs, offsets, N);
    fill_kernel<<<eb, 256, 0, stream>>>(src, e, dst, offsets, cursor, ev, E);

    aggregate_kernel<<<(N + 3) / 4, 256, 0, stream>>>(h_bf, ev, offsets, hnb, N);

    dim3 ggrid(nrb, 4);
    gemm_kernel<0><<<ggrid, 256, 0, stream>>>(hnb, W1, b1, x1b, nullptr, N);
    gemm_kernel<1><<<ggrid, 256, 0, stream>>>(x1b, W2, b2, x2b, partial, N);

    bn_finalize_kernel<<<1, 256, 0, stream>>>(partial, gamma, beta, scaleshift, nrb, N);
    bn_apply_kernel<<<2048, 256, 0, stream>>>(out, x2b, hnb, scaleshift, (long)(NB / 4));
}

// Round 4
// 276.072 us; speedup vs baseline: 1.7155x; 1.7155x over previous
//
#include <hip/hip_runtime.h>

#define D 256

typedef __attribute__((ext_vector_type(8))) short bf16x8;
typedef __attribute__((ext_vector_type(4))) float f32x4;

__device__ __forceinline__ unsigned short bfr(float x) {
    unsigned u = __float_as_uint(x);
    unsigned r = (u + 0x7fffu + ((u >> 16) & 1u)) >> 16;
    return (unsigned short)r;
}
__device__ __forceinline__ float bf2f(unsigned short u) {
    return __uint_as_float(((unsigned)u) << 16);
}

// ---------------- fp32 -> bf16 convert ----------------
__global__ void cvt_kernel(const float* __restrict__ in, unsigned short* __restrict__ out, long n4) {
    long stride = (long)gridDim.x * blockDim.x;
    for (long i = (long)blockIdx.x * blockDim.x + threadIdx.x; i < n4; i += stride) {
        float4 v = reinterpret_cast<const float4*>(in)[i];
        ushort4 o;
        o.x = bfr(v.x); o.y = bfr(v.y); o.z = bfr(v.z); o.w = bfr(v.w);
        reinterpret_cast<ushort4*>(out)[i] = o;
    }
}

// ---------------- CSR build ----------------
__global__ void hist_kernel(const int* __restrict__ dst, int* __restrict__ counts, int E) {
    int i = blockIdx.x * blockDim.x + threadIdx.x;
    if (i < E) atomicAdd(&counts[dst[i]], 1);
}

__global__ void scan1_kernel(const int* __restrict__ counts, int* __restrict__ blocksums, int n) {
    int b = blockIdx.x, t = threadIdx.x;
    int base = b * 1024 + t * 4;
    int s = 0;
    if (base + 3 < n) {
        int4 c = *reinterpret_cast<const int4*>(&counts[base]);
        s = c.x + c.y + c.z + c.w;
    } else {
        for (int i = 0; i < 4; ++i) if (base + i < n) s += counts[base + i];
    }
    int lane = t & 63, w = t >> 6;
    for (int off = 1; off < 64; off <<= 1) s += __shfl_xor(s, off, 64);
    __shared__ int ws_[4];
    if (lane == 0) ws_[w] = s;
    __syncthreads();
    if (t == 0) blocksums[b] = ws_[0] + ws_[1] + ws_[2] + ws_[3];
}

__global__ void scan2_kernel(const int* __restrict__ blocksums, int* __restrict__ blockoffs, int nb) {
    int lane = threadIdx.x;
    int v = (lane < nb) ? blocksums[lane] : 0;
    for (int off = 1; off < 64; off <<= 1) {
        int u = __shfl_up(v, off, 64);
        if (lane >= off) v += u;
    }
    if (lane < nb) blockoffs[lane] = v;
}

__global__ void scan3_kernel(const int* __restrict__ counts, const int* __restrict__ blockoffs,
                             int* __restrict__ offsets, int n) {
    int b = blockIdx.x, t = threadIdx.x;
    int base = b * 1024 + t * 4;
    int c0 = 0, c1 = 0, c2 = 0, c3 = 0;
    if (base + 3 < n) {
        int4 c = *reinterpret_cast<const int4*>(&counts[base]);
        c0 = c.x; c1 = c.y; c2 = c.z; c3 = c.w;
    } else {
        if (base + 0 < n) c0 = counts[base + 0];
        if (base + 1 < n) c1 = counts[base + 1];
        if (base + 2 < n) c2 = counts[base + 2];
        if (base + 3 < n) c3 = counts[base + 3];
    }
    int s0 = c0, s1 = s0 + c1, s2 = s1 + c2, s3 = s2 + c3;
    int lane = t & 63, w = t >> 6;
    int v = s3;
    for (int off = 1; off < 64; off <<= 1) {
        int u = __shfl_up(v, off, 64);
        if (lane >= off) v += u;
    }
    __shared__ int wsum[4];
    if (lane == 63) wsum[w] = v;
    __syncthreads();
    int woff = 0;
#pragma unroll
    for (int i = 0; i < 4; ++i) if (i < w) woff += wsum[i];
    int bo = b ? blockoffs[b - 1] : 0;
    int p = bo + woff + (v - s3);
    if (base + 0 < n) offsets[base + 1] = p + s0;
    if (base + 1 < n) offsets[base + 2] = p + s1;
    if (base + 2 < n) offsets[base + 3] = p + s2;
    if (base + 3 < n) offsets[base + 4] = p + s3;
    if (b == 0 && t == 0) offsets[0] = 0;
}

__global__ void fill_kernel(const int* __restrict__ src, const float* __restrict__ e,
                            const int* __restrict__ dst, const int* __restrict__ offsets,
                            int* __restrict__ cursor, int2* __restrict__ ev, int E) {
    int i = blockIdx.x * blockDim.x + threadIdx.x;
    if (i < E) {
        int d = dst[i];
        int p = offsets[d] + atomicAdd(&cursor[d], 1);
        ev[p] = make_int2(src[i], __float_as_int(e[i]));
    }
}

// ---------------- aggregation: one wave per node, bf16 gather ----------------
__global__ void aggregate_kernel(const unsigned short* __restrict__ hb, const int2* __restrict__ ev,
                                 const int* __restrict__ offsets, unsigned short* __restrict__ hnb,
                                 int n_nodes) {
    int wid = blockIdx.x * 4 + (threadIdx.x >> 6);
    if (wid >= n_nodes) return;
    int lane = threadIdx.x & 63;
    int beg = offsets[wid], end = offsets[wid + 1];
    float ax = 0.f, ay = 0.f, az = 0.f, aw = 0.f;
    int k = beg;
    for (; k + 8 <= end; k += 8) {
        int2 ee[8];
        ushort4 hh[8];
#pragma unroll
        for (int u = 0; u < 8; ++u) ee[u] = ev[k + u];
#pragma unroll
        for (int u = 0; u < 8; ++u)
            hh[u] = *reinterpret_cast<const ushort4*>(&hb[(size_t)ee[u].x * D + lane * 4]);
#pragma unroll
        for (int u = 0; u < 8; ++u) {
            float w0 = __int_as_float(ee[u].y);
            ax += bf2f(hh[u].x) * w0; ay += bf2f(hh[u].y) * w0;
            az += bf2f(hh[u].z) * w0; aw += bf2f(hh[u].w) * w0;
        }
    }
    for (; k + 4 <= end; k += 4) {
        int2 e0 = ev[k], e1 = ev[k + 1], e2 = ev[k + 2], e3 = ev[k + 3];
        ushort4 h0 = *reinterpret_cast<const ushort4*>(&hb[(size_t)e0.x * D + lane * 4]);
        ushort4 h1 = *reinterpret_cast<const ushort4*>(&hb[(size_t)e1.x * D + lane * 4]);
        ushort4 h2 = *reinterpret_cast<const ushort4*>(&hb[(size_t)e2.x * D + lane * 4]);
        ushort4 h3 = *reinterpret_cast<const ushort4*>(&hb[(size_t)e3.x * D + lane * 4]);
        float w0 = __int_as_float(e0.y), w1 = __int_as_float(e1.y);
        float w2 = __int_as_float(e2.y), w3 = __int_as_float(e3.y);
        ax += bf2f(h0.x) * w0 + bf2f(h1.x) * w1 + bf2f(h2.x) * w2 + bf2f(h3.x) * w3;
        ay += bf2f(h0.y) * w0 + bf2f(h1.y) * w1 + bf2f(h2.y) * w2 + bf2f(h3.y) * w3;
        az += bf2f(h0.z) * w0 + bf2f(h1.z) * w1 + bf2f(h2.z) * w2 + bf2f(h3.z) * w3;
        aw += bf2f(h0.w) * w0 + bf2f(h1.w) * w1 + bf2f(h2.w) * w2 + bf2f(h3.w) * w3;
    }
    for (; k < end; ++k) {
        int2 e0 = ev[k];
        ushort4 h0 = *reinterpret_cast<const ushort4*>(&hb[(size_t)e0.x * D + lane * 4]);
        float w0 = __int_as_float(e0.y);
        ax += bf2f(h0.x) * w0; ay += bf2f(h0.y) * w0;
        az += bf2f(h0.z) * w0; aw += bf2f(h0.w) * w0;
    }
    int deg = end - beg;
    float inv = (deg > 0) ? (1.0f / (float)deg) : 0.0f;
    ushort4 o;
    o.x = bfr(ax * inv); o.y = bfr(ay * inv); o.z = bfr(az * inv); o.w = bfr(aw * inv);
    *reinterpret_cast<ushort4*>(&hnb[(size_t)wid * D + lane * 4]) = o;
}

// ---------------- bf16 MFMA GEMM ----------------
// FUSE_STATS: emit per-row-block column sum/sumsq partials, TRANSPOSED: partial[c][bx].
template <int FUSE_STATS>
__global__ __launch_bounds__(256) void gemm_kernel(const unsigned short* __restrict__ A,
                                                   const float* __restrict__ W,
                                                   const float* __restrict__ bias,
                                                   unsigned short* __restrict__ Cout,
                                                   float* __restrict__ partial, int nrbp, int M) {
    __shared__ short As[64 * 256];
    __shared__ short Ws[64 * 256];
    const int t = threadIdx.x;
    const int row0 = blockIdx.x * 64;
    const int col0 = blockIdx.y * 64;

#pragma unroll
    for (int it = 0; it < 8; ++it) {
        int p = it * 4096 + t * 16;
        int r = p >> 9;
        int grow = row0 + r;
        float4 v = make_float4(0.f, 0.f, 0.f, 0.f);
        if (grow < M)
            v = *reinterpret_cast<const float4*>(reinterpret_cast<const char*>(A) +
                                                 (size_t)grow * 512 + (p & 511));
        *reinterpret_cast<float4*>(reinterpret_cast<char*>(As) + (p ^ ((r & 7) << 4))) = v;
    }
#pragma unroll
    for (int it = 0; it < 8; ++it) {
        int p = it * 4096 + t * 16;
        int r = p >> 9;
        const float* wsrc = W + (size_t)(col0 + r) * D + ((p & 511) >> 1);
        float4 w0 = *reinterpret_cast<const float4*>(wsrc);
        float4 w1 = *reinterpret_cast<const float4*>(wsrc + 4);
        bf16x8 pk;
        pk[0] = (short)bfr(w0.x); pk[1] = (short)bfr(w0.y);
        pk[2] = (short)bfr(w0.z); pk[3] = (short)bfr(w0.w);
        pk[4] = (short)bfr(w1.x); pk[5] = (short)bfr(w1.y);
        pk[6] = (short)bfr(w1.z); pk[7] = (short)bfr(w1.w);
        *reinterpret_cast<bf16x8*>(reinterpret_cast<char*>(Ws) + (p ^ ((r & 7) << 4))) = pk;
    }
    __syncthreads();

    const int lane = t & 63;
    const int w = t >> 6;
    const int wr = (w >> 1) * 32;
    const int wc = (w & 1) * 32;
    const int lr = lane & 15;
    const int q = lane >> 4;
    const int swz = (lane & 7) << 4;

    f32x4 zero = {0.f, 0.f, 0.f, 0.f};
    f32x4 acc[2][2] = {{zero, zero}, {zero, zero}};

#pragma unroll
    for (int k0 = 0; k0 < 256; k0 += 32) {
        int kb = k0 * 2 + q * 16;
        bf16x8 a0 = *reinterpret_cast<const bf16x8*>(reinterpret_cast<const char*>(As) +
                                                     (((wr + lr) * 512 + kb) ^ swz));
        bf16x8 a1 = *reinterpret_cast<const bf16x8*>(reinterpret_cast<const char*>(As) +
                                                     (((wr + 16 + lr) * 512 + kb) ^ swz));
        bf16x8 b0 = *reinterpret_cast<const bf16x8*>(reinterpret_cast<const char*>(Ws) +
                                                     (((wc + lr) * 512 + kb) ^ swz));
        bf16x8 b1 = *reinterpret_cast<const bf16x8*>(reinterpret_cast<const char*>(Ws) +
                                                     (((wc + 16 + lr) * 512 + kb) ^ swz));
        acc[0][0] = __builtin_amdgcn_mfma_f32_16x16x32_bf16(a0, b0, acc[0][0], 0, 0, 0);
        acc[0][1] = __builtin_amdgcn_mfma_f32_16x16x32_bf16(a0, b1, acc[0][1], 0, 0, 0);
        acc[1][0] = __builtin_amdgcn_mfma_f32_16x16x32_bf16(a1, b0, acc[1][0], 0, 0, 0);
        acc[1][1] = __builtin_amdgcn_mfma_f32_16x16x32_bf16(a1, b1, acc[1][1], 0, 0, 0);
    }

    float csum[2] = {0.f, 0.f}, csq[2] = {0.f, 0.f};
#pragma unroll
    for (int i = 0; i < 2; ++i) {
#pragma unroll
        for (int j = 0; j < 2; ++j) {
            int col = col0 + wc + j * 16 + lr;
            float bv = bias[col];
#pragma unroll
            for (int r = 0; r < 4; ++r) {
                int row = row0 + wr + i * 16 + q * 4 + r;
                if (row < M) {
                    float v = fmaxf(acc[i][j][r] + bv, 0.f);
                    Cout[(size_t)row * D + col] = bfr(v);
                    if (FUSE_STATS) { csum[j] += v; csq[j] += v * v; }
                }
            }
        }
    }

    if (FUSE_STATS) {
        __shared__ float cs_s[2][2][2][16];
        __shared__ float cq_s[2][2][2][16];
#pragma unroll
        for (int j = 0; j < 2; ++j) {
            float s = csum[j], qq = csq[j];
            s += __shfl_xor(s, 16, 64); s += __shfl_xor(s, 32, 64);
            qq += __shfl_xor(qq, 16, 64); qq += __shfl_xor(qq, 32, 64);
            if (lane < 16) { cs_s[w >> 1][w & 1][j][lane] = s; cq_s[w >> 1][w & 1][j][lane] = qq; }
        }
        __syncthreads();
        if (w < 2 && lane < 16) {
#pragma unroll
            for (int j = 0; j < 2; ++j) {
                int gcol = col0 + (w & 1) * 32 + j * 16 + lane;
                float S = cs_s[0][w & 1][j][lane] + cs_s[1][w & 1][j][lane];
                float Q = cq_s[0][w & 1][j][lane] + cq_s[1][w & 1][j][lane];
                partial[(size_t)gcol * nrbp + blockIdx.x] = S;
                partial[(size_t)(gcol + 256) * nrbp + blockIdx.x] = Q;
            }
        }
    }
}

// one block per channel c; coalesced reads of partial[c][*] and partial[c+256][*]
__global__ void bn_finalize_kernel(const float* __restrict__ partial, const float* __restrict__ gamma,
                                   const float* __restrict__ beta, float* __restrict__ scaleshift,
                                   int nrb, int nrbp, int n) {
    int c = blockIdx.x;
    int t = threadIdx.x;
    float s = 0.f, q = 0.f;
    for (int b = t; b < nrb; b += 256) {
        s += partial[(size_t)c * nrbp + b];
        q += partial[(size_t)(c + 256) * nrbp + b];
    }
    int lane = t & 63, w = t >> 6;
    for (int off = 1; off < 64; off <<= 1) {
        s += __shfl_xor(s, off, 64);
        q += __shfl_xor(q, off, 64);
    }
    __shared__ float ss[4], qs[4];
    if (lane == 0) { ss[w] = s; qs[w] = q; }
    __syncthreads();
    if (t == 0) {
        float S = ss[0] + ss[1] + ss[2] + ss[3];
        float Q = qs[0] + qs[1] + qs[2] + qs[3];
        float mu = S / (float)n;
        float var = Q / (float)n - mu * mu;
        float rs = rsqrtf(var + 1e-5f);
        float sc = gamma[c] * rs;
        scaleshift[c] = sc;
        scaleshift[D + c] = beta[c] - mu * sc;
    }
}

__global__ void bn_apply_kernel(float* __restrict__ out, const unsigned short* __restrict__ x2b,
                                const unsigned short* __restrict__ hnb,
                                const float* __restrict__ scaleshift, long total4) {
    long stride = (long)gridDim.x * blockDim.x;
    for (long i = (long)blockIdx.x * blockDim.x + threadIdx.x; i < total4; i += stride) {
        int c4 = (int)(i & 63);
        ushort4 xu = reinterpret_cast<const ushort4*>(x2b)[i];
        ushort4 hu = reinterpret_cast<const ushort4*>(hnb)[i];
        float4 sc = reinterpret_cast<const float4*>(scaleshift)[c4];
        float4 sh = reinterpret_cast<const float4*>(scaleshift)[64 + c4];
        float4 v;
        v.x = bf2f(xu.x) * sc.x + sh.x + bf2f(hu.x);
        v.y = bf2f(xu.y) * sc.y + sh.y + bf2f(hu.y);
        v.z = bf2f(xu.z) * sc.z + sh.z + bf2f(hu.z);
        v.w = bf2f(xu.w) * sc.w + sh.w + bf2f(hu.w);
        reinterpret_cast<float4*>(out)[i] = v;
    }
}

extern "C" void kernel_launch(void* const* d_in, const int* in_sizes, int n_in,
                              void* d_out, int out_size, void* d_ws, size_t ws_size,
                              hipStream_t stream) {
    const float* h     = (const float*)d_in[0];
    const float* e     = (const float*)d_in[1];
    const int*   src   = (const int*)d_in[2];
    const int*   dst   = (const int*)d_in[3];
    const float* W1    = (const float*)d_in[4];
    const float* b1    = (const float*)d_in[5];
    const float* W2    = (const float*)d_in[6];
    const float* b2    = (const float*)d_in[7];
    const float* gamma = (const float*)d_in[8];
    const float* beta  = (const float*)d_in[9];
    float* out = (float*)d_out;

    const int N = in_sizes[0] / D;
    const int E = in_sizes[2];
    const size_t NB = (size_t)N * D;
    const int nrb = (N + 63) / 64;
    const int nrbp = (nrb + 15) & ~15;
    const int nb1 = (N + 1023) / 1024;

    char* ws = (char*)d_ws;
    unsigned short* h_bf = (unsigned short*)ws; ws += NB * 2;   // dead after aggregate
    unsigned short* hnb  = (unsigned short*)ws; ws += NB * 2;
    unsigned short* x1b  = (unsigned short*)ws; ws += NB * 2;
    int2* ev             = (int2*)ws;           ws += (size_t)E * 8;
    float* partial       = (float*)ws;          ws += (size_t)512 * nrbp * 4;
    float* scaleshift    = (float*)ws;          ws += 2 * D * sizeof(float);
    int* offsets         = (int*)ws;            ws += (size_t)(N + 1) * 4;
    int* counts          = (int*)ws;            ws += (size_t)N * 4;
    int* cursor          = (int*)ws;            ws += (size_t)N * 4;
    int* blocksums       = (int*)ws;            ws += 64 * 4;
    int* blockoffs       = (int*)ws;            ws += 64 * 4;
    unsigned short* x2b  = h_bf;                // alias: reuse h_bf region

    hipMemsetAsync(counts, 0, (size_t)2 * N * 4, stream);

    cvt_kernel<<<2048, 256, 0, stream>>>(h, h_bf, (long)(NB / 4));

    int eb = (E + 255) / 256;
    hist_kernel<<<eb, 256, 0, stream>>>(dst, counts, E);
    scan1_kernel<<<nb1, 256, 0, stream>>>(counts, blocksums, N);
    scan2_kernel<<<1, 64, 0, stream>>>(blocksums, blockoffs, nb1);
    scan3_kernel<<<nb1, 256, 0, stream>>>(counts, blockoffs, offsets, N);
    fill_kernel<<<eb, 256, 0, stream>>>(src, e, dst, offsets, cursor, ev, E);

    aggregate_kernel<<<(N + 3) / 4, 256, 0, stream>>>(h_bf, ev, offsets, hnb, N);

    dim3 ggrid(nrb, 4);
    gemm_kernel<0><<<ggrid, 256, 0, stream>>>(hnb, W1, b1, x1b, nullptr, nrbp, N);
    gemm_kernel<1><<<ggrid, 256, 0, stream>>>(x1b, W2, b2, x2b, partial, nrbp, N);

    bn_finalize_kernel<<<256, 256, 0, stream>>>(partial, gamma, beta, scaleshift, nrb, nrbp, N);
    bn_apply_kernel<<<2048, 256, 0, stream>>>(out, x2b, hnb, scaleshift, (long)(NB / 4));
}

// Round 5
// 250.339 us; speedup vs baseline: 1.8918x; 1.1028x over previous
//
#include <hip/hip_runtime.h>

#define D 256

typedef __attribute__((ext_vector_type(8))) short bf16x8;
typedef __attribute__((ext_vector_type(4))) float f32x4;

__device__ __forceinline__ unsigned short bfr(float x) {
    unsigned u = __float_as_uint(x);
    unsigned r = (u + 0x7fffu + ((u >> 16) & 1u)) >> 16;
    return (unsigned short)r;
}
__device__ __forceinline__ float bf2f(unsigned short u) {
    return __uint_as_float(((unsigned)u) << 16);
}

// ---------------- fp32->bf16 convert + degree histogram (fused) ----------------
__global__ void cvt_hist_kernel(const float* __restrict__ in, unsigned short* __restrict__ out,
                                long n4, const int* __restrict__ dst, int* __restrict__ counts,
                                int E) {
    long stride = (long)gridDim.x * blockDim.x;
    long i0 = (long)blockIdx.x * blockDim.x + threadIdx.x;
    for (long i = i0; i < n4; i += stride) {
        float4 v = reinterpret_cast<const float4*>(in)[i];
        ushort4 o;
        o.x = bfr(v.x); o.y = bfr(v.y); o.z = bfr(v.z); o.w = bfr(v.w);
        reinterpret_cast<ushort4*>(out)[i] = o;
    }
    for (long i = i0; i < E; i += stride) atomicAdd(&counts[dst[i]], 1);
}

// ---------------- CSR scan (2 kernels) ----------------
__global__ void scan1_kernel(const int* __restrict__ counts, int* __restrict__ blocksums, int n) {
    int b = blockIdx.x, t = threadIdx.x;
    int base = b * 1024 + t * 4;
    int s = 0;
    if (base + 3 < n) {
        int4 c = *reinterpret_cast<const int4*>(&counts[base]);
        s = c.x + c.y + c.z + c.w;
    } else {
        for (int i = 0; i < 4; ++i) if (base + i < n) s += counts[base + i];
    }
    int lane = t & 63, w = t >> 6;
    for (int off = 1; off < 64; off <<= 1) s += __shfl_xor(s, off, 64);
    __shared__ int ws_[4];
    if (lane == 0) ws_[w] = s;
    __syncthreads();
    if (t == 0) blocksums[b] = ws_[0] + ws_[1] + ws_[2] + ws_[3];
}

// local scan + in-kernel block-offset scan (nb <= 64)
__global__ void scan3_kernel(const int* __restrict__ counts, const int* __restrict__ blocksums,
                             int* __restrict__ offsets, int n, int nb) {
    __shared__ int bo_s;
    int b = blockIdx.x, t = threadIdx.x;
    if (t < 64) {
        int v = (t < nb) ? blocksums[t] : 0;
#pragma unroll
        for (int off = 1; off < 64; off <<= 1) {
            int u = __shfl_up(v, off, 64);
            if (t >= off) v += u;
        }
        int bo = (b == 0) ? 0 : __shfl(v, b - 1, 64);
        if (t == 0) bo_s = bo;
    }
    __syncthreads();
    int base = b * 1024 + t * 4;
    int c0 = 0, c1 = 0, c2 = 0, c3 = 0;
    if (base + 3 < n) {
        int4 c = *reinterpret_cast<const int4*>(&counts[base]);
        c0 = c.x; c1 = c.y; c2 = c.z; c3 = c.w;
    } else {
        if (base + 0 < n) c0 = counts[base + 0];
        if (base + 1 < n) c1 = counts[base + 1];
        if (base + 2 < n) c2 = counts[base + 2];
        if (base + 3 < n) c3 = counts[base + 3];
    }
    int s0 = c0, s1 = s0 + c1, s2 = s1 + c2, s3 = s2 + c3;
    int lane = t & 63, w = t >> 6;
    int v = s3;
    for (int off = 1; off < 64; off <<= 1) {
        int u = __shfl_up(v, off, 64);
        if (lane >= off) v += u;
    }
    __shared__ int wsum[4];
    if (lane == 63) wsum[w] = v;
    __syncthreads();
    int woff = 0;
#pragma unroll
    for (int i = 0; i < 4; ++i) if (i < w) woff += wsum[i];
    int p = bo_s + woff + (v - s3);
    if (base + 0 < n) offsets[base + 1] = p + s0;
    if (base + 1 < n) offsets[base + 2] = p + s1;
    if (base + 2 < n) offsets[base + 3] = p + s2;
    if (base + 3 < n) offsets[base + 4] = p + s3;
    if (b == 0 && t == 0) offsets[0] = 0;
}

__global__ void fill_kernel(const int* __restrict__ src, const float* __restrict__ e,
                            const int* __restrict__ dst, const int* __restrict__ offsets,
                            int* __restrict__ cursor, int2* __restrict__ ev, int E) {
    int i = blockIdx.x * blockDim.x + threadIdx.x;
    if (i < E) {
        int d = dst[i];
        int p = offsets[d] + atomicAdd(&cursor[d], 1);
        ev[p] = make_int2(src[i], __float_as_int(e[i]));
    }
}

// ---------------- aggregation: one wave per node, bf16 gather ----------------
__global__ void aggregate_kernel(const unsigned short* __restrict__ hb, const int2* __restrict__ ev,
                                 const int* __restrict__ offsets, unsigned short* __restrict__ hnb,
                                 int n_nodes) {
    int wid = blockIdx.x * 4 + (threadIdx.x >> 6);
    if (wid >= n_nodes) return;
    int lane = threadIdx.x & 63;
    int beg = offsets[wid], end = offsets[wid + 1];
    float ax = 0.f, ay = 0.f, az = 0.f, aw = 0.f;
    int k = beg;
    for (; k + 8 <= end; k += 8) {
        int2 ee[8];
        ushort4 hh[8];
#pragma unroll
        for (int u = 0; u < 8; ++u) ee[u] = ev[k + u];
#pragma unroll
        for (int u = 0; u < 8; ++u)
            hh[u] = *reinterpret_cast<const ushort4*>(&hb[(size_t)ee[u].x * D + lane * 4]);
#pragma unroll
        for (int u = 0; u < 8; ++u) {
            float w0 = __int_as_float(ee[u].y);
            ax += bf2f(hh[u].x) * w0; ay += bf2f(hh[u].y) * w0;
            az += bf2f(hh[u].z) * w0; aw += bf2f(hh[u].w) * w0;
        }
    }
    for (; k < end; ++k) {
        int2 e0 = ev[k];
        ushort4 h0 = *reinterpret_cast<const ushort4*>(&hb[(size_t)e0.x * D + lane * 4]);
        float w0 = __int_as_float(e0.y);
        ax += bf2f(h0.x) * w0; ay += bf2f(h0.y) * w0;
        az += bf2f(h0.z) * w0; aw += bf2f(h0.w) * w0;
    }
    int deg = end - beg;
    float inv = (deg > 0) ? (1.0f / (float)deg) : 0.0f;
    ushort4 o;
    o.x = bfr(ax * inv); o.y = bfr(ay * inv); o.z = bfr(az * inv); o.w = bfr(aw * inv);
    *reinterpret_cast<ushort4*>(&hnb[(size_t)wid * D + lane * 4]) = o;
}

// ---------------- fused 2-layer MLP (MFMA) + BN stats partials ----------------
// x1 = relu(hn@W1^T+b1) lives only in LDS; x2 = relu(x1@W2^T+b2) -> global bf16 + per-wave
// column sum/sumsq partials (transposed layout partial[c][bx*4+w]).
__global__ __launch_bounds__(256) void mlp_kernel(const unsigned short* __restrict__ A,
                                                  const float* __restrict__ W1,
                                                  const float* __restrict__ b1,
                                                  const float* __restrict__ W2,
                                                  const float* __restrict__ b2,
                                                  unsigned short* __restrict__ X2out,
                                                  float* __restrict__ partial, int P4, int M) {
    __shared__ short Ah[64 * 256];   // 32KB: hn tile, later reused as x2 tile
    __shared__ short X1[64 * 256];   // 32KB
    __shared__ short Wt[32 * 256];   // 16KB: current weight subtile
    const int t = threadIdx.x;
    const int row0 = blockIdx.x * 64;

    // stage hn tile (swizzled)
#pragma unroll
    for (int it = 0; it < 8; ++it) {
        int p = it * 4096 + t * 16;
        int r = p >> 9;
        int grow = row0 + r;
        float4 v = make_float4(0.f, 0.f, 0.f, 0.f);
        if (grow < M)
            v = *reinterpret_cast<const float4*>(reinterpret_cast<const char*>(A) +
                                                 (size_t)grow * 512 + (p & 511));
        *reinterpret_cast<float4*>(reinterpret_cast<char*>(Ah) + (p ^ ((r & 7) << 4))) = v;
    }

    const int lane = t & 63;
    const int w = t >> 6;
    const int wr = w * 16;            // wave's 16-row slice
    const int lr = lane & 15;
    const int q = lane >> 4;
    const int swz = (lane & 7) << 4;

    // ---- layer 1: X1 (LDS only) ----
    for (int cs = 0; cs < 8; ++cs) {
        __syncthreads();
#pragma unroll
        for (int it = 0; it < 4; ++it) {
            int p = it * 4096 + t * 16;
            int r = p >> 9;
            const float* wsrc = W1 + (size_t)(cs * 32 + r) * D + ((p & 511) >> 1);
            float4 w0 = *reinterpret_cast<const float4*>(wsrc);
            float4 w1v = *reinterpret_cast<const float4*>(wsrc + 4);
            bf16x8 pk;
            pk[0] = (short)bfr(w0.x); pk[1] = (short)bfr(w0.y);
            pk[2] = (short)bfr(w0.z); pk[3] = (short)bfr(w0.w);
            pk[4] = (short)bfr(w1v.x); pk[5] = (short)bfr(w1v.y);
            pk[6] = (short)bfr(w1v.z); pk[7] = (short)bfr(w1v.w);
            *reinterpret_cast<bf16x8*>(reinterpret_cast<char*>(Wt) + (p ^ ((r & 7) << 4))) = pk;
        }
        __syncthreads();
        f32x4 acc0 = {0.f, 0.f, 0.f, 0.f}, acc1 = {0.f, 0.f, 0.f, 0.f};
#pragma unroll
        for (int k0 = 0; k0 < 256; k0 += 32) {
            int kb = k0 * 2 + q * 16;
            bf16x8 a = *reinterpret_cast<const bf16x8*>(reinterpret_cast<const char*>(Ah) +
                                                        (((wr + lr) * 512 + kb) ^ swz));
            bf16x8 bb0 = *reinterpret_cast<const bf16x8*>(reinterpret_cast<const char*>(Wt) +
                                                          ((lr * 512 + kb) ^ swz));
            bf16x8 bb1 = *reinterpret_cast<const bf16x8*>(reinterpret_cast<const char*>(Wt) +
                                                          (((16 + lr) * 512 + kb) ^ swz));
            acc0 = __builtin_amdgcn_mfma_f32_16x16x32_bf16(a, bb0, acc0, 0, 0, 0);
            acc1 = __builtin_amdgcn_mfma_f32_16x16x32_bf16(a, bb1, acc1, 0, 0, 0);
        }
#pragma unroll
        for (int j = 0; j < 2; ++j) {
            const f32x4& ac = j ? acc1 : acc0;
            int col = cs * 32 + j * 16 + lr;
            float bv = b1[col];
#pragma unroll
            for (int r = 0; r < 4; ++r) {
                int row = wr + q * 4 + r;
                float v = fmaxf(ac[r] + bv, 0.f);
                *reinterpret_cast<short*>(reinterpret_cast<char*>(X1) +
                                          ((row * 512 + col * 2) ^ ((row & 7) << 4))) = (short)bfr(v);
            }
        }
    }

    // ---- layer 2: x2 -> Ah region + stats partials ----
    for (int cs = 0; cs < 8; ++cs) {
        __syncthreads();
#pragma unroll
        for (int it = 0; it < 4; ++it) {
            int p = it * 4096 + t * 16;
            int r = p >> 9;
            const float* wsrc = W2 + (size_t)(cs * 32 + r) * D + ((p & 511) >> 1);
            float4 w0 = *reinterpret_cast<const float4*>(wsrc);
            float4 w1v = *reinterpret_cast<const float4*>(wsrc + 4);
            bf16x8 pk;
            pk[0] = (short)bfr(w0.x); pk[1] = (short)bfr(w0.y);
            pk[2] = (short)bfr(w0.z); pk[3] = (short)bfr(w0.w);
            pk[4] = (short)bfr(w1v.x); pk[5] = (short)bfr(w1v.y);
            pk[6] = (short)bfr(w1v.z); pk[7] = (short)bfr(w1v.w);
            *reinterpret_cast<bf16x8*>(reinterpret_cast<char*>(Wt) + (p ^ ((r & 7) << 4))) = pk;
        }
        __syncthreads();
        f32x4 acc0 = {0.f, 0.f, 0.f, 0.f}, acc1 = {0.f, 0.f, 0.f, 0.f};
#pragma unroll
        for (int k0 = 0; k0 < 256; k0 += 32) {
            int kb = k0 * 2 + q * 16;
            bf16x8 a = *reinterpret_cast<const bf16x8*>(reinterpret_cast<const char*>(X1) +
                                                        (((wr + lr) * 512 + kb) ^ swz));
            bf16x8 bb0 = *reinterpret_cast<const bf16x8*>(reinterpret_cast<const char*>(Wt) +
                                                          ((lr * 512 + kb) ^ swz));
            bf16x8 bb1 = *reinterpret_cast<const bf16x8*>(reinterpret_cast<const char*>(Wt) +
                                                          (((16 + lr) * 512 + kb) ^ swz));
            acc0 = __builtin_amdgcn_mfma_f32_16x16x32_bf16(a, bb0, acc0, 0, 0, 0);
            acc1 = __builtin_amdgcn_mfma_f32_16x16x32_bf16(a, bb1, acc1, 0, 0, 0);
        }
        float csum[2] = {0.f, 0.f}, csq[2] = {0.f, 0.f};
#pragma unroll
        for (int j = 0; j < 2; ++j) {
            const f32x4& ac = j ? acc1 : acc0;
            int col = cs * 32 + j * 16 + lr;
            float bv = b2[col];
#pragma unroll
            for (int r = 0; r < 4; ++r) {
                int row = wr + q * 4 + r;
                float v = fmaxf(ac[r] + bv, 0.f);
                *reinterpret_cast<short*>(reinterpret_cast<char*>(Ah) +
                                          ((row * 512 + col * 2) ^ ((row & 7) << 4))) = (short)bfr(v);
                if (row0 + row < M) { csum[j] += v; csq[j] += v * v; }
            }
        }
#pragma unroll
        for (int j = 0; j < 2; ++j) {
            float s = csum[j], qq = csq[j];
            s += __shfl_xor(s, 16, 64); s += __shfl_xor(s, 32, 64);
            qq += __shfl_xor(qq, 16, 64); qq += __shfl_xor(qq, 32, 64);
            if (lane < 16) {
                int col = cs * 32 + j * 16 + lane;
                partial[(size_t)col * P4 + blockIdx.x * 4 + w] = s;
                partial[(size_t)(col + 256) * P4 + blockIdx.x * 4 + w] = qq;
            }
        }
    }

    // ---- stream x2 tile to global (coalesced bf16x8) ----
    __syncthreads();
#pragma unroll
    for (int it = 0; it < 8; ++it) {
        int p = it * 4096 + t * 16;
        int r = p >> 9;
        int grow = row0 + r;
        if (grow < M) {
            bf16x8 v = *reinterpret_cast<const bf16x8*>(reinterpret_cast<const char*>(Ah) +
                                                        (p ^ ((r & 7) << 4)));
            *reinterpret_cast<bf16x8*>(reinterpret_cast<char*>(X2out) + (size_t)grow * 512 +
                                       (p & 511)) = v;
        }
    }
}

// one block per channel c; coalesced reads of partial[c][*]
__global__ void bn_finalize_kernel(const float* __restrict__ partial, const float* __restrict__ gamma,
                                   const float* __restrict__ beta, float* __restrict__ scaleshift,
                                   int nrb4, int P4, int n) {
    int c = blockIdx.x;
    int t = threadIdx.x;
    float s = 0.f, q = 0.f;
    for (int b = t; b < nrb4; b += 256) {
        s += partial[(size_t)c * P4 + b];
        q += partial[(size_t)(c + 256) * P4 + b];
    }
    int lane = t & 63, w = t >> 6;
    for (int off = 1; off < 64; off <<= 1) {
        s += __shfl_xor(s, off, 64);
        q += __shfl_xor(q, off, 64);
    }
    __shared__ float ss[4], qs[4];
    if (lane == 0) { ss[w] = s; qs[w] = q; }
    __syncthreads();
    if (t == 0) {
        float S = ss[0] + ss[1] + ss[2] + ss[3];
        float Q = qs[0] + qs[1] + qs[2] + qs[3];
        float mu = S / (float)n;
        float var = Q / (float)n - mu * mu;
        float rs = rsqrtf(var + 1e-5f);
        float sc = gamma[c] * rs;
        scaleshift[c] = sc;
        scaleshift[D + c] = beta[c] - mu * sc;
    }
}

__global__ void bn_apply_kernel(float* __restrict__ out, const unsigned short* __restrict__ x2b,
                                const unsigned short* __restrict__ hnb,
                                const float* __restrict__ scaleshift, long total4) {
    long stride = (long)gridDim.x * blockDim.x;
    for (long i = (long)blockIdx.x * blockDim.x + threadIdx.x; i < total4; i += stride) {
        int c4 = (int)(i & 63);
        ushort4 xu = reinterpret_cast<const ushort4*>(x2b)[i];
        ushort4 hu = reinterpret_cast<const ushort4*>(hnb)[i];
        float4 sc = reinterpret_cast<const float4*>(scaleshift)[c4];
        float4 sh = reinterpret_cast<const float4*>(scaleshift)[64 + c4];
        float4 v;
        v.x = bf2f(xu.x) * sc.x + sh.x + bf2f(hu.x);
        v.y = bf2f(xu.y) * sc.y + sh.y + bf2f(hu.y);
        v.z = bf2f(xu.z) * sc.z + sh.z + bf2f(hu.z);
        v.w = bf2f(xu.w) * sc.w + sh.w + bf2f(hu.w);
        reinterpret_cast<float4*>(out)[i] = v;
    }
}

extern "C" void kernel_launch(void* const* d_in, const int* in_sizes, int n_in,
                              void* d_out, int out_size, void* d_ws, size_t ws_size,
                              hipStream_t stream) {
    const float* h     = (const float*)d_in[0];
    const float* e     = (const float*)d_in[1];
    const int*   src   = (const int*)d_in[2];
    const int*   dst   = (const int*)d_in[3];
    const float* W1    = (const float*)d_in[4];
    const float* b1    = (const float*)d_in[5];
    const float* W2    = (const float*)d_in[6];
    const float* b2    = (const float*)d_in[7];
    const float* gamma = (const float*)d_in[8];
    const float* beta  = (const float*)d_in[9];
    float* out = (float*)d_out;

    const int N = in_sizes[0] / D;
    const int E = in_sizes[2];
    const size_t NB = (size_t)N * D;
    const int nrb = (N + 63) / 64;
    const int nrb4 = nrb * 4;
    const int P4 = (nrb4 + 15) & ~15;
    const int nb1 = (N + 1023) / 1024;

    char* ws = (char*)d_ws;
    unsigned short* h_bf = (unsigned short*)ws; ws += NB * 2;   // dead after aggregate
    unsigned short* hnb  = (unsigned short*)ws; ws += NB * 2;
    int2* ev             = (int2*)ws;           ws += (size_t)E * 8;
    float* partial       = (float*)ws;          ws += (size_t)512 * P4 * 4;
    float* scaleshift    = (float*)ws;          ws += 2 * D * sizeof(float);
    int* offsets         = (int*)ws;            ws += (size_t)(N + 1) * 4;
    int* counts          = (int*)ws;            ws += (size_t)N * 4;
    int* cursor          = (int*)ws;            ws += (size_t)N * 4;
    int* blocksums       = (int*)ws;            ws += 64 * 4;
    unsigned short* x2b  = h_bf;                // alias: reuse h_bf region

    hipMemsetAsync(counts, 0, (size_t)2 * N * 4, stream);

    cvt_hist_kernel<<<2048, 256, 0, stream>>>(h, h_bf, (long)(NB / 4), dst, counts, E);
    scan1_kernel<<<nb1, 256, 0, stream>>>(counts, blocksums, N);
    scan3_kernel<<<nb1, 256, 0, stream>>>(counts, blocksums, offsets, N, nb1);
    fill_kernel<<<(E + 255) / 256, 256, 0, stream>>>(src, e, dst, offsets, cursor, ev, E);

    aggregate_kernel<<<(N + 3) / 4, 256, 0, stream>>>(h_bf, ev, offsets, hnb, N);

    mlp_kernel<<<nrb, 256, 0, stream>>>(hnb, W1, b1, W2, b2, x2b, partial, P4, N);

    bn_finalize_kernel<<<256, 256, 0, stream>>>(partial, gamma, beta, scaleshift, nrb4, P4, N);
    bn_apply_kernel<<<2048, 256, 0, stream>>>(out, x2b, hnb, scaleshift, (long)(NB / 4));
}